// Round 1
// baseline (686.569 us; speedup 1.0000x reference)
//
#include <hip/hip_runtime.h>
#include <hip/hip_cooperative_groups.h>
#include <stdint.h>

// GRID=4096, windows (128,256,512) centered at (2048,2048).
// Output = [3,4096,4096] float masks flat, then 3 counts.
#define GRID_N 4096
#define NBLK 1024           // cooperative grid: 4 blocks/CU x 256 CUs
#define CCL_BLOCKS 336      // 16 + 64 + 256 tiles of 32x32
#define CELL_BLOCKS 1344    // 64 + 256 + 1024 blocks of 256 (one thread per cell)
#define NUM_EDGES 19712     // boundary-cell edges: 768 + 3584 + 15360
// fallback (non-cooperative) path sizes
#define TILE_BLOCKS 336
#define EDGE_BLOCKS 77
#define ZERO_BLOCKS 8192

typedef float vfloat4 __attribute__((ext_vector_type(4)));

namespace cg = cooperative_groups;

// ---- window decode for cell-per-thread work (256 threads/block) ----
__device__ inline void decode_block(int b, int& w, int& S, int& lg, int& off,
                                    int& woff, int& baseblk) {
    if (b < 64)       { w = 0; S = 128; lg = 7; off = 1984; woff = 0;     baseblk = 0;   }
    else if (b < 320) { w = 1; S = 256; lg = 8; off = 1920; woff = 16384; baseblk = 64;  }
    else              { w = 2; S = 512; lg = 9; off = 1792; woff = 81920; baseblk = 320; }
}

// ---- tile decode (32x32 tile per block) ----
__device__ inline void decode_tile(int b, int& S, int& lg, int& off, int& woff,
                                   int& tileR, int& tileC) {
    int t, tsh;
    if (b < 16)      { S = 128; lg = 7; off = 1984; woff = 0;     t = b;      tsh = 2; }
    else if (b < 80) { S = 256; lg = 8; off = 1920; woff = 16384; t = b - 16; tsh = 3; }
    else             { S = 512; lg = 9; off = 1792; woff = 81920; t = b - 80; tsh = 4; }
    tileR = t >> tsh;
    tileC = t & ((1 << tsh) - 1);
}

// ---- global union-find with path-halving (device scope) ----
// Invariant: parent < node always (unions attach larger root under smaller),
// so walks strictly decrease and terminate; halving CAS writes an existing
// grandparent, preserving the invariant under races.
__device__ inline int uf_find(int* L, int a) {
    while (true) {
        int p = __hip_atomic_load(&L[a], __ATOMIC_RELAXED, __HIP_MEMORY_SCOPE_AGENT);
        if (p == a) return a;
        int gp = __hip_atomic_load(&L[p], __ATOMIC_RELAXED, __HIP_MEMORY_SCOPE_AGENT);
        if (gp == p) return p;
        __hip_atomic_compare_exchange_strong(&L[a], &p, gp,
            __ATOMIC_RELAXED, __ATOMIC_RELAXED, __HIP_MEMORY_SCOPE_AGENT);
        a = gp;
    }
}
__device__ inline void uf_union(int* L, int a, int b) {
    while (true) {
        a = uf_find(L, a);
        b = uf_find(L, b);
        if (a == b) return;
        if (a < b) { int t = a; a = b; b = t; }   // a > b: attach a under b
        int old = atomicMin(&L[a], b);
        if (old == a) return;                      // was a root, attached
        a = old;                                   // lost race: merge old link too
    }
}

// ---- LDS union-find (workgroup scope, only inside one tile) ----
// lfind now does CAS path-halving (same invariant argument as uf_find; a
// plain store would race with atomicMin on ex-roots, CAS cannot clobber).
__device__ inline int lfind(int* lab, int a) {
    while (true) {
        int p = __hip_atomic_load(&lab[a], __ATOMIC_RELAXED, __HIP_MEMORY_SCOPE_WORKGROUP);
        if (p == a) return a;
        int gp = __hip_atomic_load(&lab[p], __ATOMIC_RELAXED, __HIP_MEMORY_SCOPE_WORKGROUP);
        if (gp == p) return p;
        __hip_atomic_compare_exchange_strong(&lab[a], &p, gp,
            __ATOMIC_RELAXED, __ATOMIC_RELAXED, __HIP_MEMORY_SCOPE_WORKGROUP);
        a = gp;
    }
}
__device__ inline void lunion(int* lab, int a, int b) {
    while (true) {
        a = lfind(lab, a);
        b = lfind(lab, b);
        if (a == b) return;
        if (a < b) { int t = a; a = b; b = t; }
        int old = atomicMin(&lab[a], b);
        if (old == a) return;
        a = old;
    }
}

// ===================== fused cooperative kernel =====================
// Phase A: blocks [0,336) do per-tile CCL in LDS -> depth-1 forest in L;
//          blocks [336,1024) zero-fill the 201 MB output (nontemporal).
//          The zero-fill has no dependency, so it fully hides the CCL.
// Phase B: first 19712 threads union tile-boundary edges (shuffle-deduped).
// Phase C: 1344 virtual cell-blocks over 1024 real blocks: reach =
//          free && find(cell)==find(center); scatter masks; counts via
//          ballot-popcount -> one float atomicAdd per virtual block.
__global__ __launch_bounds__(256, 4)
void k_fused(const float* __restrict__ mask, int* __restrict__ L,
             float* __restrict__ out, int out_size) {
    __shared__ int lab[1024];
    __shared__ int rootC;
    __shared__ float wsum[4];
    const int b = blockIdx.x;
    const int tid = threadIdx.x;

    // ---------------- Phase A ----------------
    if (b < CCL_BLOCKS) {
        int S, lg, off, woff, tileR, tileC;
        decode_tile(b, S, lg, off, woff, tileR, tileC);
        (void)lg;
        #pragma unroll
        for (int k = 0; k < 4; k++) {
            int l = tid + k * 256;
            int lr = l >> 5, lc = l & 31;
            size_t g = (size_t)(off + tileR * 32 + lr) * GRID_N
                     + (size_t)(off + tileC * 32 + lc);
            lab[l] = (mask[g] == 0.0f) ? l : -1;
        }
        __syncthreads();
        #pragma unroll
        for (int k = 0; k < 4; k++) {
            int l = tid + k * 256;
            if (lab[l] == -1) continue;
            int lr = l >> 5, lc = l & 31;
            if (lc + 1 < 32 && lab[l + 1] != -1)  lunion(lab, l, l + 1);
            if (lr + 1 < 32 && lab[l + 32] != -1) lunion(lab, l, l + 32);
        }
        __syncthreads();
        #pragma unroll
        for (int k = 0; k < 4; k++) {
            int l = tid + k * 256;
            int lr = l >> 5, lc = l & 31;
            int gidx = (tileR * 32 + lr) * S + tileC * 32 + lc;
            if (lab[l] == -1) {
                L[woff + gidx] = -1;
            } else {
                int r = lfind(lab, l);
                int rr = r >> 5, rc = r & 31;
                L[woff + gidx] = (tileR * 32 + rr) * S + tileC * 32 + rc;
            }
        }
    } else {
        long long n4 = (long long)(out_size >> 2);
        long long i = (long long)(b - CCL_BLOCKS) * 256 + tid;
        const long long stride = (long long)(NBLK - CCL_BLOCKS) * 256;
        vfloat4* o4 = (vfloat4*)out;
        vfloat4 z = (vfloat4)(0.0f);
        for (; i < n4; i += stride) __builtin_nontemporal_store(z, &o4[i]);
        long long t = (long long)(b - CCL_BLOCKS) * 256 + tid;
        long long tail = (long long)out_size - n4 * 4;
        if (t < tail) out[n4 * 4 + t] = 0.0f;   // the 3 count slots
    }
    __threadfence();
    cg::this_grid().sync();

    // ---------------- Phase B: boundary edge unions ----------------
    {
        int e = b * 256 + tid;
        if (e < NUM_EDGES) {
            // ranges: [0,384) w0-v, [384,768) w0-h, [768,2560) w1-v,
            //         [2560,4352) w1-h, [4352,12032) w2-v, [12032,19712) w2-h
            int S, lg, woff, i; bool vert;
            if (e < 768)        { S = 128; lg = 7; woff = 0;     vert = e < 384;   i = vert ? e : e - 384; }
            else if (e < 4352)  { S = 256; lg = 8; woff = 16384; vert = e < 2560;  i = vert ? e - 768 : e - 2560; }
            else                { S = 512; lg = 9; woff = 81920; vert = e < 12032; i = vert ? e - 4352 : e - 12032; }
            int line = i >> lg;
            int pos = i & (S - 1);
            int* Lw = L + woff;
            int a, n;
            if (vert) { int c = line * 32 + 31; a = pos * S + c; n = a + 1; }
            else      { int r = line * 32 + 31; a = r * S + pos; n = a + S; }
            int la = Lw[a];            // tile-root labels; leaves never rewritten
            int ln = Lw[n];
            int pla = __shfl_up(la, 1);
            int pln = __shfl_up(ln, 1);
            bool first = ((pos & 31) == 0);   // first cell of this tile edge
            if (la != -1 && ln != -1 && (first || la != pla || ln != pln))
                uf_union(Lw, la, ln);
        }
    }
    __threadfence();
    cg::this_grid().sync();

    // ---------------- Phase C: write masks + counts ----------------
    for (int vb = b; vb < CELL_BLOCKS; vb += NBLK) {
        int w, S, lg, off, woff, baseblk;
        decode_block(vb, w, S, lg, off, woff, baseblk);
        int idx = (vb - baseblk) * 256 + tid;
        int* Lw = L + woff;
        if (tid == 0) {
            int centerIdx = (S >> 1) * S + (S >> 1);   // center always free (setup)
            rootC = uf_find(Lw, centerIdx);
        }
        __syncthreads();
        int lb = Lw[idx];
        bool reach = false;
        if (lb != -1) reach = (uf_find(Lw, lb) == rootC);
        int r = idx >> lg;
        int c = idx & (S - 1);
        size_t go = (size_t)w * GRID_N * GRID_N + (size_t)(off + r) * GRID_N + (size_t)(off + c);
        out[go] = reach ? 1.0f : 0.0f;
        unsigned long long m = __ballot(reach);
        int lane = tid & 63;
        int wv = tid >> 6;
        if (lane == 0) wsum[wv] = (float)__popcll(m);
        __syncthreads();
        if (tid == 0) {
            float s = wsum[0] + wsum[1] + wsum[2] + wsum[3];
            atomicAdd(&out[(size_t)3 * GRID_N * GRID_N + w], s);
        }
        __syncthreads();   // protect rootC/wsum reuse on second iteration
    }
}

// ===================== fallback (proven 3-kernel path) =====================
__global__ void k_local(const float* __restrict__ mask, int* __restrict__ L) {
    int S, lg, off, woff, tileR, tileC;
    decode_tile(blockIdx.x, S, lg, off, woff, tileR, tileC);
    (void)lg;
    __shared__ int lab[1024];
    #pragma unroll
    for (int k = 0; k < 4; k++) {
        int l = threadIdx.x + k * 256;
        int lr = l >> 5, lc = l & 31;
        size_t g = (size_t)(off + tileR * 32 + lr) * GRID_N
                 + (size_t)(off + tileC * 32 + lc);
        lab[l] = (mask[g] == 0.0f) ? l : -1;
    }
    __syncthreads();
    #pragma unroll
    for (int k = 0; k < 4; k++) {
        int l = threadIdx.x + k * 256;
        if (lab[l] == -1) continue;
        int lr = l >> 5, lc = l & 31;
        if (lc + 1 < 32 && lab[l + 1] != -1)  lunion(lab, l, l + 1);
        if (lr + 1 < 32 && lab[l + 32] != -1) lunion(lab, l, l + 32);
    }
    __syncthreads();
    #pragma unroll
    for (int k = 0; k < 4; k++) {
        int l = threadIdx.x + k * 256;
        int lr = l >> 5, lc = l & 31;
        int gidx = (tileR * 32 + lr) * S + tileC * 32 + lc;
        if (lab[l] == -1) {
            L[woff + gidx] = -1;
        } else {
            int r = lfind(lab, l);
            int rr = r >> 5, rc = r & 31;
            L[woff + gidx] = (tileR * 32 + rr) * S + tileC * 32 + rc;
        }
    }
}

__global__ void k_zero_merge(int* __restrict__ L, float* __restrict__ out,
                             int out_size) {
    int b = blockIdx.x;
    if (b < EDGE_BLOCKS) {
        int e = b * 256 + threadIdx.x;
        int S, lg, woff, i; bool vert;
        if (e < 768)        { S = 128; lg = 7; woff = 0;     vert = e < 384;   i = vert ? e : e - 384; }
        else if (e < 4352)  { S = 256; lg = 8; woff = 16384; vert = e < 2560;  i = vert ? e - 768 : e - 2560; }
        else                { S = 512; lg = 9; woff = 81920; vert = e < 12032; i = vert ? e - 4352 : e - 12032; }
        int line = i >> lg;
        int pos = i & (S - 1);
        int* Lw = L + woff;
        int a, n;
        if (vert) { int c = line * 32 + 31; a = pos * S + c; n = a + 1; }
        else      { int r = line * 32 + 31; a = r * S + pos; n = a + S; }
        int la = Lw[a];
        int ln = Lw[n];
        int pla = __shfl_up(la, 1);
        int pln = __shfl_up(ln, 1);
        bool first = ((pos & 31) == 0);
        if (la != -1 && ln != -1 && (first || la != pla || ln != pln))
            uf_union(Lw, la, ln);
    } else {
        long long n4 = (long long)(out_size >> 2);
        long long i = (long long)(b - EDGE_BLOCKS) * 256 + threadIdx.x;
        long long stride = (long long)ZERO_BLOCKS * 256;
        vfloat4* o4 = (vfloat4*)out;
        vfloat4 z = (vfloat4)(0.0f);
        for (; i < n4; i += stride) __builtin_nontemporal_store(z, &o4[i]);
        long long t = (long long)(b - EDGE_BLOCKS) * 256 + threadIdx.x;
        long long tail = (long long)out_size - n4 * 4;
        if (t < tail) out[n4 * 4 + t] = 0.0f;
    }
}

__global__ void k_write(int* __restrict__ L, float* __restrict__ out) {
    int b = blockIdx.x;
    int w, S, lg, off, woff, baseblk;
    decode_block(b, w, S, lg, off, woff, baseblk);
    int idx = (b - baseblk) * 256 + threadIdx.x;
    int* Lw = L + woff;
    __shared__ int rootC;
    __shared__ float wsum[4];
    if (threadIdx.x == 0) {
        int centerIdx = (S >> 1) * S + (S >> 1);
        rootC = uf_find(Lw, centerIdx);
    }
    __syncthreads();
    int lb = Lw[idx];
    bool reach = false;
    if (lb != -1) reach = (uf_find(Lw, lb) == rootC);
    int r = idx >> lg;
    int c = idx & (S - 1);
    size_t go = (size_t)w * GRID_N * GRID_N + (size_t)(off + r) * GRID_N + (size_t)(off + c);
    out[go] = reach ? 1.0f : 0.0f;
    unsigned long long m = __ballot(reach);
    int lane = threadIdx.x & 63;
    int wv = threadIdx.x >> 6;
    if (lane == 0) wsum[wv] = (float)__popcll(m);
    __syncthreads();
    if (threadIdx.x == 0) {
        float s = wsum[0] + wsum[1] + wsum[2] + wsum[3];
        atomicAdd(&out[(size_t)3 * GRID_N * GRID_N + w], s);
    }
}

extern "C" void kernel_launch(void* const* d_in, const int* in_sizes, int n_in,
                              void* d_out, int out_size, void* d_ws, size_t ws_size,
                              hipStream_t stream) {
    const float* mask = (const float*)d_in[0];
    float* out = (float*)d_out;
    int* L = (int*)d_ws;   // 344064 * 4 B = 1.35 MB of workspace
    int osz = out_size;

    void* args[] = { (void*)&mask, (void*)&L, (void*)&out, (void*)&osz };
    hipError_t err = hipLaunchCooperativeKernel((const void*)k_fused,
                                                dim3(NBLK), dim3(256),
                                                args, 0u, stream);
    if (err != hipSuccess) {
        // fallback: proven non-cooperative 3-kernel path
        k_local<<<TILE_BLOCKS, 256, 0, stream>>>(mask, L);
        k_zero_merge<<<EDGE_BLOCKS + ZERO_BLOCKS, 256, 0, stream>>>(L, out, osz);
        k_write<<<CELL_BLOCKS, 256, 0, stream>>>(L, out);
    }
}

// Round 2
// 268.985 us; speedup vs baseline: 2.5524x; 2.5524x over previous
//
#include <hip/hip_runtime.h>
#include <stdint.h>

// GRID=4096, windows (128,256,512) centered at (2048,2048).
// Output = [3,4096,4096] float masks flat, then 3 counts.
#define GRID_N 4096
#define CCL_BLOCKS 336      // 16 + 64 + 256 tiles of 32x32
#define ZERO_BLOCKS 8192    // streaming zero-fill of the 201 MB output
#define K1_BLOCKS (CCL_BLOCKS + ZERO_BLOCKS)
#define CELL_BLOCKS 1344    // 64 + 256 + 1024 blocks of 256 (one thread per cell)
#define NUM_EDGES 19712     // boundary-cell edges: 768 + 3584 + 15360
#define EDGE_BLOCKS 77      // 19712 / 256

typedef float vfloat4 __attribute__((ext_vector_type(4)));

// ---- window decode for cell-per-thread kernels (256 threads/block) ----
__device__ inline void decode_block(int b, int& w, int& S, int& lg, int& off,
                                    int& woff, int& baseblk) {
    if (b < 64)       { w = 0; S = 128; lg = 7; off = 1984; woff = 0;     baseblk = 0;   }
    else if (b < 320) { w = 1; S = 256; lg = 8; off = 1920; woff = 16384; baseblk = 64;  }
    else              { w = 2; S = 512; lg = 9; off = 1792; woff = 81920; baseblk = 320; }
}

// ---- tile decode (32x32 tile per block) ----
__device__ inline void decode_tile(int b, int& S, int& lg, int& off, int& woff,
                                   int& tileR, int& tileC) {
    int t, tsh;
    if (b < 16)      { S = 128; lg = 7; off = 1984; woff = 0;     t = b;      tsh = 2; }
    else if (b < 80) { S = 256; lg = 8; off = 1920; woff = 16384; t = b - 16; tsh = 3; }
    else             { S = 512; lg = 9; off = 1792; woff = 81920; t = b - 80; tsh = 4; }
    tileR = t >> tsh;
    tileC = t & ((1 << tsh) - 1);
}

// ---- global union-find with path-halving (device scope) ----
// Invariant: parent < node always (unions attach larger root under smaller),
// so walks strictly decrease and terminate; halving CAS writes an existing
// grandparent, preserving the invariant under races.
__device__ inline int uf_find(int* L, int a) {
    while (true) {
        int p = __hip_atomic_load(&L[a], __ATOMIC_RELAXED, __HIP_MEMORY_SCOPE_AGENT);
        if (p == a) return a;
        int gp = __hip_atomic_load(&L[p], __ATOMIC_RELAXED, __HIP_MEMORY_SCOPE_AGENT);
        if (gp == p) return p;
        __hip_atomic_compare_exchange_strong(&L[a], &p, gp,
            __ATOMIC_RELAXED, __ATOMIC_RELAXED, __HIP_MEMORY_SCOPE_AGENT);
        a = gp;
    }
}
__device__ inline void uf_union(int* L, int a, int b) {
    while (true) {
        a = uf_find(L, a);
        b = uf_find(L, b);
        if (a == b) return;
        if (a < b) { int t = a; a = b; b = t; }   // a > b: attach a under b
        int old = atomicMin(&L[a], b);
        if (old == a) return;                      // was a root, attached
        a = old;                                   // lost race: merge old link too
    }
}

// ---- LDS union-find (workgroup scope, only inside one tile) ----
// Proven simple-walk version (no halving; chains inside a 32x32 tile stay
// short enough, and this was the measured-274us configuration).
__device__ inline int lfind(int* lab, int a) {
    int p = __hip_atomic_load(&lab[a], __ATOMIC_RELAXED, __HIP_MEMORY_SCOPE_WORKGROUP);
    while (p != a) {
        a = p;
        p = __hip_atomic_load(&lab[a], __ATOMIC_RELAXED, __HIP_MEMORY_SCOPE_WORKGROUP);
    }
    return a;
}
__device__ inline void lunion(int* lab, int a, int b) {
    while (true) {
        a = lfind(lab, a);
        b = lfind(lab, b);
        if (a == b) return;
        if (a < b) { int t = a; a = b; b = t; }
        int old = atomicMin(&lab[a], b);
        if (old == a) return;
        a = old;
    }
}

// K1: blocks [0,336): per-tile CCL in LDS -> depth-1 global forest
//     (window-linear indices), blocked = -1.
//     blocks [336, 8528): zero-fill the 201 MB output with nontemporal
//     float4 (no dependency on CCL, so it runs from t=0 and hides it).
__global__ void k_ccl_zero(const float* __restrict__ mask, int* __restrict__ L,
                           float* __restrict__ out, int out_size) {
    const int b = blockIdx.x;
    if (b < CCL_BLOCKS) {
        int S, lg, off, woff, tileR, tileC;
        decode_tile(b, S, lg, off, woff, tileR, tileC);
        (void)lg;
        __shared__ int lab[1024];

        #pragma unroll
        for (int k = 0; k < 4; k++) {
            int l = threadIdx.x + k * 256;
            int lr = l >> 5, lc = l & 31;
            size_t g = (size_t)(off + tileR * 32 + lr) * GRID_N
                     + (size_t)(off + tileC * 32 + lc);
            lab[l] = (mask[g] == 0.0f) ? l : -1;
        }
        __syncthreads();

        #pragma unroll
        for (int k = 0; k < 4; k++) {
            int l = threadIdx.x + k * 256;
            if (lab[l] == -1) continue;
            int lr = l >> 5, lc = l & 31;
            if (lc + 1 < 32 && lab[l + 1] != -1)  lunion(lab, l, l + 1);
            if (lr + 1 < 32 && lab[l + 32] != -1) lunion(lab, l, l + 32);
        }
        __syncthreads();

        #pragma unroll
        for (int k = 0; k < 4; k++) {
            int l = threadIdx.x + k * 256;
            int lr = l >> 5, lc = l & 31;
            int gidx = (tileR * 32 + lr) * S + tileC * 32 + lc;
            if (lab[l] == -1) {
                L[woff + gidx] = -1;
            } else {
                int r = lfind(lab, l);
                int rr = r >> 5, rc = r & 31;
                L[woff + gidx] = (tileR * 32 + rr) * S + tileC * 32 + rc;
            }
        }
    } else {
        long long n4 = (long long)(out_size >> 2);
        long long i = (long long)(b - CCL_BLOCKS) * 256 + threadIdx.x;
        const long long stride = (long long)ZERO_BLOCKS * 256;
        vfloat4* o4 = (vfloat4*)out;
        vfloat4 z = (vfloat4)(0.0f);
        for (; i < n4; i += stride) __builtin_nontemporal_store(z, &o4[i]);
        long long t = (long long)(b - CCL_BLOCKS) * 256 + threadIdx.x;
        long long tail = (long long)out_size - n4 * 4;
        if (t < tail) out[n4 * 4 + t] = 0.0f;   // the 3 count slots
    }
}

// K2: union tile-boundary edges (one edge cell per thread, wave-shuffle
// dedupe of identical label pairs -> ~1-2K real unions).
// Edge ordering: within each boundary line, the 32 cells of one tile-edge are
// consecutive in e, so lane-1 shuffle compares within the same tile edge.
__global__ void k_edges(int* __restrict__ L) {
    int e = blockIdx.x * 256 + threadIdx.x;
    // ranges: [0,384) w0-v, [384,768) w0-h, [768,2560) w1-v,
    //         [2560,4352) w1-h, [4352,12032) w2-v, [12032,19712) w2-h
    int S, lg, woff, i; bool vert;
    if (e < 768)        { S = 128; lg = 7; woff = 0;     vert = e < 384;   i = vert ? e : e - 384; }
    else if (e < 4352)  { S = 256; lg = 8; woff = 16384; vert = e < 2560;  i = vert ? e - 768 : e - 2560; }
    else                { S = 512; lg = 9; woff = 81920; vert = e < 12032; i = vert ? e - 4352 : e - 12032; }
    int line = i >> lg;            // which boundary line
    int pos = i & (S - 1);         // position along the line
    int* Lw = L + woff;
    int a, n;
    if (vert) { int c = line * 32 + 31; a = pos * S + c; n = a + 1; }
    else      { int r = line * 32 + 31; a = r * S + pos; n = a + S; }
    int la = Lw[a];                // tile-root labels; stable during K2
    int ln = Lw[n];                // (halving never rewrites leaf cells)
    int pla = __shfl_up(la, 1);
    int pln = __shfl_up(ln, 1);
    bool first = ((pos & 31) == 0);   // first cell of this tile edge
    if (la != -1 && ln != -1 && (first || la != pla || ln != pln))
        uf_union(Lw, la, ln);
}

// K3: reach = free && find(cell)==find(center); scatter window masks; counts
// via ballot-popcount -> one float atomicAdd per block (counts < 2^24 exact).
// NEW: wave-dedupe of uf_find — 64 consecutive window cells span only 2-3
// tiles, so a wave holds ~2-4 distinct tile-root labels. Ballot-loop: leader
// lane walks the chain once, result broadcast by shuffle. Cuts device-scope
// find/CAS traffic ~16-30x.
__global__ void k_write(int* __restrict__ L, float* __restrict__ out) {
    int b = blockIdx.x;
    int w, S, lg, off, woff, baseblk;
    decode_block(b, w, S, lg, off, woff, baseblk);
    int idx = (b - baseblk) * 256 + threadIdx.x;
    int* Lw = L + woff;

    __shared__ int rootC;
    __shared__ float wsum[4];
    if (threadIdx.x == 0) {
        int centerIdx = (S >> 1) * S + (S >> 1);   // center is always free (setup)
        rootC = uf_find(Lw, centerIdx);
    }
    __syncthreads();

    int lb = Lw[idx];
    int root = -1;
    unsigned long long need = __ballot(lb != -1);
    while (need) {
        int leader = __builtin_ctzll(need);
        int llab = __shfl(lb, leader);
        int lroot = 0;
        if ((threadIdx.x & 63) == leader) lroot = uf_find(Lw, llab);
        lroot = __shfl(lroot, leader);
        bool match = (lb == llab);
        if (match) root = lroot;
        need &= ~__ballot(match);
    }
    bool reach = (lb != -1) && (root == rootC);

    int r = idx >> lg;
    int c = idx & (S - 1);
    size_t go = (size_t)w * GRID_N * GRID_N + (size_t)(off + r) * GRID_N + (size_t)(off + c);
    out[go] = reach ? 1.0f : 0.0f;

    unsigned long long m = __ballot(reach);
    int lane = threadIdx.x & 63;
    int wv = threadIdx.x >> 6;
    if (lane == 0) wsum[wv] = (float)__popcll(m);
    __syncthreads();
    if (threadIdx.x == 0) {
        float s = wsum[0] + wsum[1] + wsum[2] + wsum[3];
        atomicAdd(&out[(size_t)3 * GRID_N * GRID_N + w], s);
    }
}

extern "C" void kernel_launch(void* const* d_in, const int* in_sizes, int n_in,
                              void* d_out, int out_size, void* d_ws, size_t ws_size,
                              hipStream_t stream) {
    const float* mask = (const float*)d_in[0];
    float* out = (float*)d_out;
    int* L = (int*)d_ws;   // 344064 * 4 B = 1.35 MB of workspace

    k_ccl_zero<<<K1_BLOCKS, 256, 0, stream>>>(mask, L, out, out_size);
    k_edges<<<EDGE_BLOCKS, 256, 0, stream>>>(L);
    k_write<<<CELL_BLOCKS, 256, 0, stream>>>(L, out);
}

// Round 3
// 263.560 us; speedup vs baseline: 2.6050x; 1.0206x over previous
//
#include <hip/hip_runtime.h>
#include <stdint.h>

// GRID=4096, windows (128,256,512) centered at (2048,2048).
// Output = [3,4096,4096] float masks flat, then 3 counts.
#define GRID_N 4096
#define CCL_BLOCKS 336      // 16 + 64 + 256 tiles of 32x32
#define ZERO_BLOCKS 8192    // streaming zero-fill of the 201 MB output
#define K1_BLOCKS (CCL_BLOCKS + ZERO_BLOCKS)
#define CELL_BLOCKS 1344    // 64 + 256 + 1024 blocks of 256 (one thread per cell)
#define NUM_EDGES 19712     // boundary-cell edges: 768 + 3584 + 15360
#define EDGE_BLOCKS 77      // 19712 / 256

typedef float vfloat4 __attribute__((ext_vector_type(4)));

// ---- window decode for cell-per-thread kernels (256 threads/block) ----
__device__ inline void decode_block(int b, int& w, int& S, int& lg, int& off,
                                    int& woff, int& baseblk) {
    if (b < 64)       { w = 0; S = 128; lg = 7; off = 1984; woff = 0;     baseblk = 0;   }
    else if (b < 320) { w = 1; S = 256; lg = 8; off = 1920; woff = 16384; baseblk = 64;  }
    else              { w = 2; S = 512; lg = 9; off = 1792; woff = 81920; baseblk = 320; }
}

// ---- tile decode (32x32 tile per block) ----
__device__ inline void decode_tile(int b, int& S, int& lg, int& off, int& woff,
                                   int& tileR, int& tileC) {
    int t, tsh;
    if (b < 16)      { S = 128; lg = 7; off = 1984; woff = 0;     t = b;      tsh = 2; }
    else if (b < 80) { S = 256; lg = 8; off = 1920; woff = 16384; t = b - 16; tsh = 3; }
    else             { S = 512; lg = 9; off = 1792; woff = 81920; t = b - 80; tsh = 4; }
    tileR = t >> tsh;
    tileC = t & ((1 << tsh) - 1);
}

// ---- global union-find with path-halving (device scope) ----
// Invariant: parent < node always (unions attach larger root under smaller),
// so walks strictly decrease and terminate; halving CAS writes an existing
// grandparent, preserving the invariant under races.
__device__ inline int uf_find(int* L, int a) {
    while (true) {
        int p = __hip_atomic_load(&L[a], __ATOMIC_RELAXED, __HIP_MEMORY_SCOPE_AGENT);
        if (p == a) return a;
        int gp = __hip_atomic_load(&L[p], __ATOMIC_RELAXED, __HIP_MEMORY_SCOPE_AGENT);
        if (gp == p) return p;
        __hip_atomic_compare_exchange_strong(&L[a], &p, gp,
            __ATOMIC_RELAXED, __ATOMIC_RELAXED, __HIP_MEMORY_SCOPE_AGENT);
        a = gp;
    }
}
__device__ inline void uf_union(int* L, int a, int b) {
    while (true) {
        a = uf_find(L, a);
        b = uf_find(L, b);
        if (a == b) return;
        if (a < b) { int t = a; a = b; b = t; }   // a > b: attach a under b
        int old = atomicMin(&L[a], b);
        if (old == a) return;                      // was a root, attached
        a = old;                                   // lost race: merge old link too
    }
}

// ---- LDS union-find (workgroup scope, only inside one tile) ----
// Proven simple-walk version (measured-269us configuration).
__device__ inline int lfind(int* lab, int a) {
    int p = __hip_atomic_load(&lab[a], __ATOMIC_RELAXED, __HIP_MEMORY_SCOPE_WORKGROUP);
    while (p != a) {
        a = p;
        p = __hip_atomic_load(&lab[a], __ATOMIC_RELAXED, __HIP_MEMORY_SCOPE_WORKGROUP);
    }
    return a;
}
__device__ inline void lunion(int* lab, int a, int b) {
    while (true) {
        a = lfind(lab, a);
        b = lfind(lab, b);
        if (a == b) return;
        if (a < b) { int t = a; a = b; b = t; }
        int old = atomicMin(&lab[a], b);
        if (old == a) return;
        a = old;
    }
}

// K1: blocks [0,336): per-tile CCL in LDS -> depth-1 global forest
//     (window-linear indices), blocked = -1.
//     blocks [336, 8528): zero-fill the 201 MB output.
//     ROUND-3 CHANGE: plain float4 stores instead of nontemporal. Plain
//     stores are the measured-6.5 TB/s path on this chip (fillBuffer,
//     m13 float4 copy); NT (L2-bypass) is unmeasured and suspected slow.
__global__ void k_ccl_zero(const float* __restrict__ mask, int* __restrict__ L,
                           float* __restrict__ out, int out_size) {
    const int b = blockIdx.x;
    if (b < CCL_BLOCKS) {
        int S, lg, off, woff, tileR, tileC;
        decode_tile(b, S, lg, off, woff, tileR, tileC);
        (void)lg;
        __shared__ int lab[1024];

        #pragma unroll
        for (int k = 0; k < 4; k++) {
            int l = threadIdx.x + k * 256;
            int lr = l >> 5, lc = l & 31;
            size_t g = (size_t)(off + tileR * 32 + lr) * GRID_N
                     + (size_t)(off + tileC * 32 + lc);
            lab[l] = (mask[g] == 0.0f) ? l : -1;
        }
        __syncthreads();

        #pragma unroll
        for (int k = 0; k < 4; k++) {
            int l = threadIdx.x + k * 256;
            if (lab[l] == -1) continue;
            int lr = l >> 5, lc = l & 31;
            if (lc + 1 < 32 && lab[l + 1] != -1)  lunion(lab, l, l + 1);
            if (lr + 1 < 32 && lab[l + 32] != -1) lunion(lab, l, l + 32);
        }
        __syncthreads();

        #pragma unroll
        for (int k = 0; k < 4; k++) {
            int l = threadIdx.x + k * 256;
            int lr = l >> 5, lc = l & 31;
            int gidx = (tileR * 32 + lr) * S + tileC * 32 + lc;
            if (lab[l] == -1) {
                L[woff + gidx] = -1;
            } else {
                int r = lfind(lab, l);
                int rr = r >> 5, rc = r & 31;
                L[woff + gidx] = (tileR * 32 + rr) * S + tileC * 32 + rc;
            }
        }
    } else {
        long long n4 = (long long)(out_size >> 2);
        long long i = (long long)(b - CCL_BLOCKS) * 256 + threadIdx.x;
        const long long stride = (long long)ZERO_BLOCKS * 256;
        vfloat4* o4 = (vfloat4*)out;
        vfloat4 z = (vfloat4)(0.0f);
        for (; i < n4; i += stride) o4[i] = z;   // plain stores (see note above)
        long long t = (long long)(b - CCL_BLOCKS) * 256 + threadIdx.x;
        long long tail = (long long)out_size - n4 * 4;
        if (t < tail) out[n4 * 4 + t] = 0.0f;   // the 3 count slots
    }
}

// K2: union tile-boundary edges (one edge cell per thread, wave-shuffle
// dedupe of identical label pairs -> ~1-2K real unions).
// Edge ordering: within each boundary line, the 32 cells of one tile-edge are
// consecutive in e, so lane-1 shuffle compares within the same tile edge.
__global__ void k_edges(int* __restrict__ L) {
    int e = blockIdx.x * 256 + threadIdx.x;
    // ranges: [0,384) w0-v, [384,768) w0-h, [768,2560) w1-v,
    //         [2560,4352) w1-h, [4352,12032) w2-v, [12032,19712) w2-h
    int S, lg, woff, i; bool vert;
    if (e < 768)        { S = 128; lg = 7; woff = 0;     vert = e < 384;   i = vert ? e : e - 384; }
    else if (e < 4352)  { S = 256; lg = 8; woff = 16384; vert = e < 2560;  i = vert ? e - 768 : e - 2560; }
    else                { S = 512; lg = 9; woff = 81920; vert = e < 12032; i = vert ? e - 4352 : e - 12032; }
    int line = i >> lg;            // which boundary line
    int pos = i & (S - 1);         // position along the line
    int* Lw = L + woff;
    int a, n;
    if (vert) { int c = line * 32 + 31; a = pos * S + c; n = a + 1; }
    else      { int r = line * 32 + 31; a = r * S + pos; n = a + S; }
    int la = Lw[a];                // tile-root labels; stable during K2
    int ln = Lw[n];                // (halving never rewrites leaf cells)
    int pla = __shfl_up(la, 1);
    int pln = __shfl_up(ln, 1);
    bool first = ((pos & 31) == 0);   // first cell of this tile edge
    if (la != -1 && ln != -1 && (first || la != pla || ln != pln))
        uf_union(Lw, la, ln);
}

// K3: reach = free && find(cell)==find(center); scatter window masks; counts
// via ballot-popcount -> one float atomicAdd per block (counts < 2^24 exact).
// Wave-dedupe of uf_find: 64 consecutive window cells span only 2-3 tiles,
// so a wave holds ~2-4 distinct tile-root labels; leader lanes walk the
// chain once, results broadcast by shuffle.
__global__ void k_write(int* __restrict__ L, float* __restrict__ out) {
    int b = blockIdx.x;
    int w, S, lg, off, woff, baseblk;
    decode_block(b, w, S, lg, off, woff, baseblk);
    int idx = (b - baseblk) * 256 + threadIdx.x;
    int* Lw = L + woff;

    __shared__ int rootC;
    __shared__ float wsum[4];
    if (threadIdx.x == 0) {
        int centerIdx = (S >> 1) * S + (S >> 1);   // center is always free (setup)
        rootC = uf_find(Lw, centerIdx);
    }
    __syncthreads();

    int lb = Lw[idx];
    int root = -1;
    unsigned long long need = __ballot(lb != -1);
    while (need) {
        int leader = __builtin_ctzll(need);
        int llab = __shfl(lb, leader);
        int lroot = 0;
        if ((threadIdx.x & 63) == leader) lroot = uf_find(Lw, llab);
        lroot = __shfl(lroot, leader);
        bool match = (lb == llab);
        if (match) root = lroot;
        need &= ~__ballot(match);
    }
    bool reach = (lb != -1) && (root == rootC);

    int r = idx >> lg;
    int c = idx & (S - 1);
    size_t go = (size_t)w * GRID_N * GRID_N + (size_t)(off + r) * GRID_N + (size_t)(off + c);
    out[go] = reach ? 1.0f : 0.0f;

    unsigned long long m = __ballot(reach);
    int lane = threadIdx.x & 63;
    int wv = threadIdx.x >> 6;
    if (lane == 0) wsum[wv] = (float)__popcll(m);
    __syncthreads();
    if (threadIdx.x == 0) {
        float s = wsum[0] + wsum[1] + wsum[2] + wsum[3];
        atomicAdd(&out[(size_t)3 * GRID_N * GRID_N + w], s);
    }
}

extern "C" void kernel_launch(void* const* d_in, const int* in_sizes, int n_in,
                              void* d_out, int out_size, void* d_ws, size_t ws_size,
                              hipStream_t stream) {
    const float* mask = (const float*)d_in[0];
    float* out = (float*)d_out;
    int* L = (int*)d_ws;   // 344064 * 4 B = 1.35 MB of workspace

    k_ccl_zero<<<K1_BLOCKS, 256, 0, stream>>>(mask, L, out, out_size);
    k_edges<<<EDGE_BLOCKS, 256, 0, stream>>>(L);
    k_write<<<CELL_BLOCKS, 256, 0, stream>>>(L, out);
}